// Round 8
// baseline (151.814 us; speedup 1.0000x reference)
//
#include <hip/hip_runtime.h>
#include <math.h>

#define EMBED_DIM 64
#define NUM_EXPERTS 4
#define LANES 64
#define TILE_CHUNKS 1024            // 64 tokens * 16 float4 = 16 KB per tile
#define NBLOCKS 1280                // 5 single-wave blocks/CU (2x16KB LDS each)

// Persistent SINGLE-WAVE blocks with an explicit depth-2 double buffer and
// counted vmcnt — round 6's structure, minus the 256-VGPR W-hoist that
// killed residency (W is re-read per tile via uniform s_loads, proven free).
// Per iteration: issue tile t+1's 16 coalesced 1KB global_load_lds into the
// other buffer, s_waitcnt vmcnt(16) (retires tile t's 16 loads + the 2 old
// stores; the 16 newest loads stay in flight across compute), compute,
// store, flip parity. Every wave thus holds 16KB posted during its compute
// -> 5 waves/CU x 16KB = 80KB in flight >> 9.6KB latency-BW product.
//
// Arithmetic is bit-identical to the passing kernels: strictly sequential
// f32 mul-then-add chain per logit (no FMA contraction; pragma disables
// -ffp-contract=fast), matching numpy einsum's sum-of-products order.
// LDS XOR chunk swizzle on BOTH sides (inverse-swizzled global source +
// swizzled ds_read) keeps the 256B-stride row reads bank-conflict-free.
__global__ __launch_bounds__(LANES) void gate_kernel(
    const float* __restrict__ x,
    const float* __restrict__ W,
    float* __restrict__ wout,     // [n,4] dense routing weights
    float* __restrict__ iout,     // [n,2] top-k indices, stored as float
    int n)
{
#pragma clang fp contract(off)
    __shared__ float4 lds[2 * TILE_CHUNKS];

    const int lane   = threadIdx.x;          // 0..63, tile-local token id
    const int ntiles = n / 64;               // 32768
    const int stride = gridDim.x;

    const float4* x4 = reinterpret_cast<const float4*>(x);
    const float4* W4 = reinterpret_cast<const float4*>(W);

    // Issue one tile's staging loads: linear LDS dest chunk L=i*64+lane,
    // global source chunk gc = (tk<<4)|(c^(tk&7)) (inverse XOR swizzle).
    auto issue = [&](int tile, int parity) {
        const size_t tileChunk = (size_t)tile * TILE_CHUNKS;
        #pragma unroll
        for (int i = 0; i < 16; ++i) {
            const int L  = i * 64 + lane;
            const int tk = L >> 4;
            const int c  = L & 15;
            const int gc = (tk << 4) | (c ^ (tk & 7));
            __builtin_amdgcn_global_load_lds(
                (const __attribute__((address_space(1))) void*)(x4 + tileChunk + gc),
                (__attribute__((address_space(3))) void*)&lds[parity * TILE_CHUNKS + i * 64],
                16, 0, 0);
        }
    };

    int t = blockIdx.x;
    if (t >= ntiles) return;

    issue(t, 0);
    int parity = 0;

    for (; t < ntiles; t += stride) {
        const int tn = t + stride;
        const bool hasnext = (tn < ntiles);
        if (hasnext) issue(tn, parity ^ 1);

        // vmcnt ledger at this point (issue order, oldest first):
        //   [loads(t):16][stores(t-1):2][loads(t+1):16]  (34 outstanding)
        // vmcnt(16) waits until only the newest 16 remain = tile t ready,
        // next tile's loads never drained. Final iteration: full drain.
        if (hasnext) { asm volatile("s_waitcnt vmcnt(16)" ::: "memory"); }
        else         { asm volatile("s_waitcnt vmcnt(0)"  ::: "memory"); }
        __builtin_amdgcn_sched_barrier(0);

        const float4* xt = &lds[parity * TILE_CHUNKS];

        float s0 = 0.0f, s1 = 0.0f, s2 = 0.0f, s3 = 0.0f;
        #pragma unroll
        for (int j = 0; j < 16; ++j) {
            const float4 xv = xt[(lane << 4) | (j ^ (lane & 7))];
            const float4 a = W4[ 0 + j];
            const float4 b = W4[16 + j];
            const float4 c = W4[32 + j];
            const float4 d = W4[48 + j];
            // strict d-order, mul rounded then add rounded (no contraction):
            s0 = s0 + xv.x * a.x; s0 = s0 + xv.y * a.y;
            s0 = s0 + xv.z * a.z; s0 = s0 + xv.w * a.w;
            s1 = s1 + xv.x * b.x; s1 = s1 + xv.y * b.y;
            s1 = s1 + xv.z * b.z; s1 = s1 + xv.w * b.w;
            s2 = s2 + xv.x * c.x; s2 = s2 + xv.y * c.y;
            s2 = s2 + xv.z * c.z; s2 = s2 + xv.w * c.w;
            s3 = s3 + xv.x * d.x; s3 = s3 + xv.y * d.y;
            s3 = s3 + xv.z * d.z; s3 = s3 + xv.w * d.w;
        }

        // top-1: strict > -> ties to LOWER index (lax.top_k semantics).
        int   i1 = 0;  float v1 = s0;
        if (s1 > v1) { v1 = s1; i1 = 1; }
        if (s2 > v1) { v1 = s2; i1 = 2; }
        if (s3 > v1) { v1 = s3; i1 = 3; }
        int   i2 = -1; float v2 = -INFINITY;
        if (i1 != 0 && s0 > v2) { v2 = s0; i2 = 0; }
        if (i1 != 1 && s1 > v2) { v2 = s1; i2 = 1; }
        if (i1 != 2 && s2 > v2) { v2 = s2; i2 = 2; }
        if (i1 != 3 && s3 > v2) { v2 = s3; i2 = 3; }

        const float e2  = expf(v2 - v1);
        const float den = 1.0f + e2;
        const float p1  = 1.0f / den;
        const float p2  = e2 / den;

        const int tok = t * 64 + lane;

        float4 wv;
        wv.x = (i1 == 0) ? p1 : ((i2 == 0) ? p2 : 0.0f);
        wv.y = (i1 == 1) ? p1 : ((i2 == 1) ? p2 : 0.0f);
        wv.z = (i1 == 2) ? p1 : ((i2 == 2) ? p2 : 0.0f);
        wv.w = (i1 == 3) ? p1 : ((i2 == 3) ? p2 : 0.0f);
        reinterpret_cast<float4*>(wout)[tok] = wv;

        float2 iv;
        iv.x = (float)i1;
        iv.y = (float)i2;
        reinterpret_cast<float2*>(iout)[tok] = iv;

        parity ^= 1;
    }
}

extern "C" void kernel_launch(void* const* d_in, const int* in_sizes, int n_in,
                              void* d_out, int out_size, void* d_ws, size_t ws_size,
                              hipStream_t stream) {
    const float* x = (const float*)d_in[0];
    const float* W = (const float*)d_in[1];
    const int n = in_sizes[0] / EMBED_DIM;   // 2097152

    float* wout = (float*)d_out;                    // n*4 floats
    float* iout = wout + (size_t)n * NUM_EXPERTS;   // n*2 indices stored as float

    hipLaunchKernelGGL(gate_kernel, dim3(NBLOCKS), dim3(LANES), 0, stream,
                       x, W, wout, iout, n);
}

// Round 9
// 116.168 us; speedup vs baseline: 1.3068x; 1.3068x over previous
//
#include <hip/hip_runtime.h>
#include <math.h>

#define EMBED_DIM 64
#define NUM_EXPERTS 4
#define THREADS 128                 // 2 INDEPENDENT waves per block
#define TILE_CHUNKS 1024            // 64 tokens * 16 float4 = 16 KB per wave
#define NBLOCKS 16384               // short-lived blocks: churn pipelining

// Round-5 churn structure (16384 short blocks — block replacement gives
// stage||compute overlap across blocks and natural de-phasing) with the
// intra-block __syncthreads REMOVED: each wave stages its own 16 KB half
// and waits only on its own vmcnt (a wave-private counter = exactly its own
// 16 global_load_lds). No cross-wave LDS sharing -> race-free. Each wave
// starts computing half a stage earlier than the barrier version.
// Persistent/counted-vmcnt variants (R6-R8) all lost to this: the compiler
// inserts its own vmcnt(0) drain before the LDS reads, defeating source-
// level software pipelining (matches the m131-m141 ledger).
//
// Arithmetic is bit-identical to the passing kernels: strictly sequential
// f32 mul-then-add chain per logit (no FMA contraction; pragma disables
// -ffp-contract=fast), matching numpy einsum's sum-of-products order.
// LDS XOR chunk swizzle on BOTH sides (inverse-swizzled global source +
// swizzled ds_read) keeps the 256B-stride row reads bank-conflict-free.
__global__ __launch_bounds__(THREADS) void gate_kernel(
    const float* __restrict__ x,
    const float* __restrict__ W,
    float* __restrict__ wout,     // [n,4] dense routing weights
    float* __restrict__ iout,     // [n,2] top-k indices, stored as float
    int n)
{
#pragma clang fp contract(off)
    __shared__ float4 lds[2 * TILE_CHUNKS];   // one 16KB tile per wave

    const int lane = threadIdx.x & 63;
    const int wid  = threadIdx.x >> 6;               // wave in block: 0/1
    const int tile = blockIdx.x * 2 + wid;           // this wave's tile
    float4* tilebuf = &lds[wid * TILE_CHUNKS];

    const float4* x4 = reinterpret_cast<const float4*>(x);
    const float4* W4 = reinterpret_cast<const float4*>(W);

    // Stage this wave's 64 rows (16 KB), fully coalesced: linear LDS dest
    // chunk L = i*64+lane; global source chunk gc = (tk<<4)|(c^(tk&7))
    // (inverse XOR swizzle; the read below applies the same XOR).
    const size_t tileChunk = (size_t)tile * TILE_CHUNKS;
    #pragma unroll
    for (int i = 0; i < 16; ++i) {
        const int L  = i * 64 + lane;
        const int tk = L >> 4;
        const int c  = L & 15;
        const int gc = (tk << 4) | (c ^ (tk & 7));
        __builtin_amdgcn_global_load_lds(
            (const __attribute__((address_space(1))) void*)(x4 + tileChunk + gc),
            (__attribute__((address_space(3))) void*)&tilebuf[i * 64],
            16, 0, 0);
    }
    // Wave-private wait: vmcnt counts only THIS wave's ops (= its 16 loads).
    asm volatile("s_waitcnt vmcnt(0)" ::: "memory");
    __builtin_amdgcn_sched_barrier(0);

    float s0 = 0.0f, s1 = 0.0f, s2 = 0.0f, s3 = 0.0f;
    #pragma unroll
    for (int j = 0; j < 16; ++j) {
        const float4 xv = tilebuf[(lane << 4) | (j ^ (lane & 7))];
        const float4 a = W4[ 0 + j];
        const float4 b = W4[16 + j];
        const float4 c = W4[32 + j];
        const float4 d = W4[48 + j];
        // strict d-order, mul rounded then add rounded (no contraction):
        s0 = s0 + xv.x * a.x; s0 = s0 + xv.y * a.y;
        s0 = s0 + xv.z * a.z; s0 = s0 + xv.w * a.w;
        s1 = s1 + xv.x * b.x; s1 = s1 + xv.y * b.y;
        s1 = s1 + xv.z * b.z; s1 = s1 + xv.w * b.w;
        s2 = s2 + xv.x * c.x; s2 = s2 + xv.y * c.y;
        s2 = s2 + xv.z * c.z; s2 = s2 + xv.w * c.w;
        s3 = s3 + xv.x * d.x; s3 = s3 + xv.y * d.y;
        s3 = s3 + xv.z * d.z; s3 = s3 + xv.w * d.w;
    }

    // top-1: strict > -> ties to LOWER index (lax.top_k semantics).
    int   i1 = 0;  float v1 = s0;
    if (s1 > v1) { v1 = s1; i1 = 1; }
    if (s2 > v1) { v1 = s2; i1 = 2; }
    if (s3 > v1) { v1 = s3; i1 = 3; }
    int   i2 = -1; float v2 = -INFINITY;
    if (i1 != 0 && s0 > v2) { v2 = s0; i2 = 0; }
    if (i1 != 1 && s1 > v2) { v2 = s1; i2 = 1; }
    if (i1 != 2 && s2 > v2) { v2 = s2; i2 = 2; }
    if (i1 != 3 && s3 > v2) { v2 = s3; i2 = 3; }

    const float e2  = expf(v2 - v1);
    const float den = 1.0f + e2;
    const float p1  = 1.0f / den;
    const float p2  = e2 / den;

    const int tok = tile * 64 + lane;

    float4 wv;
    wv.x = (i1 == 0) ? p1 : ((i2 == 0) ? p2 : 0.0f);
    wv.y = (i1 == 1) ? p1 : ((i2 == 1) ? p2 : 0.0f);
    wv.z = (i1 == 2) ? p1 : ((i2 == 2) ? p2 : 0.0f);
    wv.w = (i1 == 3) ? p1 : ((i2 == 3) ? p2 : 0.0f);
    reinterpret_cast<float4*>(wout)[tok] = wv;

    float2 iv;
    iv.x = (float)i1;
    iv.y = (float)i2;
    reinterpret_cast<float2*>(iout)[tok] = iv;
}

extern "C" void kernel_launch(void* const* d_in, const int* in_sizes, int n_in,
                              void* d_out, int out_size, void* d_ws, size_t ws_size,
                              hipStream_t stream) {
    const float* x = (const float*)d_in[0];
    const float* W = (const float*)d_in[1];
    const int n = in_sizes[0] / EMBED_DIM;   // 2097152

    float* wout = (float*)d_out;                    // n*4 floats
    float* iout = wout + (size_t)n * NUM_EXPERTS;   // n*2 indices stored as float

    hipLaunchKernelGGL(gate_kernel, dim3(NBLOCKS), dim3(THREADS), 0, stream,
                       x, W, wout, iout, n);
}

// Round 10
// 115.330 us; speedup vs baseline: 1.3163x; 1.0073x over previous
//
#include <hip/hip_runtime.h>
#include <math.h>

#define EMBED_DIM 64
#define NUM_EXPERTS 4
#define THREADS 128                 // 2 INDEPENDENT waves per block
#define TILE_CHUNKS 1024            // 64 tokens * 16 float4 = 16 KB per wave
#define NBLOCKS 16384               // short-lived blocks: churn pipelining

// R9 structure (short churn blocks, independent waves, no barrier) but the
// staging path is REG-STAGING instead of global_load_lds: 16 perfectly
// coalesced global_load_dwordx4 into registers, then 16 ds_write_b128 with
// the XOR chunk swizzle applied at the WRITE (global loads are purely
// linear; the swizzle lives entirely in the LDS domain, matching the
// proven read-side XOR). This probes whether the global_load_lds DMA path
// (TA walks 8 lines per instr + LDS write-port contention) was capping
// both R5 and R9 at ~116us; the compiler can also interleave ds_writes
// with arriving loads (vmcnt staircase) instead of one monolithic drain.
//
// Arithmetic is bit-identical to the passing kernels: strictly sequential
// f32 mul-then-add chain per logit (no FMA contraction; pragma disables
// -ffp-contract=fast), matching numpy einsum's sum-of-products order.
__global__ __launch_bounds__(THREADS) void gate_kernel(
    const float* __restrict__ x,
    const float* __restrict__ W,
    float* __restrict__ wout,     // [n,4] dense routing weights
    float* __restrict__ iout,     // [n,2] top-k indices, stored as float
    int n)
{
#pragma clang fp contract(off)
    __shared__ float4 lds[2 * TILE_CHUNKS];   // one 16KB tile per wave

    const int lane = threadIdx.x & 63;
    const int wid  = threadIdx.x >> 6;               // wave in block: 0/1
    const int tile = blockIdx.x * 2 + wid;           // this wave's tile
    float4* tilebuf = &lds[wid * TILE_CHUNKS];

    const float4* x4 = reinterpret_cast<const float4*>(x);
    const float4* W4 = reinterpret_cast<const float4*>(W);

    // 16 linear, fully-coalesced loads: global chunk G = i*64 + lane.
    const size_t tileChunk = (size_t)tile * TILE_CHUNKS;
    float4 r[16];
    #pragma unroll
    for (int i = 0; i < 16; ++i) {
        r[i] = x4[tileChunk + i * 64 + lane];
    }

    // Swizzled LDS writes: global chunk G=(tk<<4)|c lands at (tk<<4)|(c^(tk&7)).
    // Per instruction the wave still writes a contiguous 1KB span (the XOR
    // permutes within 256B rows) -> conflict-free. Compiler interleaves
    // these with the arriving loads via a vmcnt staircase.
    #pragma unroll
    for (int i = 0; i < 16; ++i) {
        const int G  = i * 64 + lane;
        const int tk = G >> 4;
        const int c  = G & 15;
        tilebuf[(tk << 4) | (c ^ (tk & 7))] = r[i];
    }
    __builtin_amdgcn_sched_barrier(0);   // keep reads below the writes

    float s0 = 0.0f, s1 = 0.0f, s2 = 0.0f, s3 = 0.0f;
    #pragma unroll
    for (int j = 0; j < 16; ++j) {
        const float4 xv = tilebuf[(lane << 4) | (j ^ (lane & 7))];
        const float4 a = W4[ 0 + j];
        const float4 b = W4[16 + j];
        const float4 c = W4[32 + j];
        const float4 d = W4[48 + j];
        // strict d-order, mul rounded then add rounded (no contraction):
        s0 = s0 + xv.x * a.x; s0 = s0 + xv.y * a.y;
        s0 = s0 + xv.z * a.z; s0 = s0 + xv.w * a.w;
        s1 = s1 + xv.x * b.x; s1 = s1 + xv.y * b.y;
        s1 = s1 + xv.z * b.z; s1 = s1 + xv.w * b.w;
        s2 = s2 + xv.x * c.x; s2 = s2 + xv.y * c.y;
        s2 = s2 + xv.z * c.z; s2 = s2 + xv.w * c.w;
        s3 = s3 + xv.x * d.x; s3 = s3 + xv.y * d.y;
        s3 = s3 + xv.z * d.z; s3 = s3 + xv.w * d.w;
    }

    // top-1: strict > -> ties to LOWER index (lax.top_k semantics).
    int   i1 = 0;  float v1 = s0;
    if (s1 > v1) { v1 = s1; i1 = 1; }
    if (s2 > v1) { v1 = s2; i1 = 2; }
    if (s3 > v1) { v1 = s3; i1 = 3; }
    int   i2 = -1; float v2 = -INFINITY;
    if (i1 != 0 && s0 > v2) { v2 = s0; i2 = 0; }
    if (i1 != 1 && s1 > v2) { v2 = s1; i2 = 1; }
    if (i1 != 2 && s2 > v2) { v2 = s2; i2 = 2; }
    if (i1 != 3 && s3 > v2) { v2 = s3; i2 = 3; }

    const float e2  = expf(v2 - v1);
    const float den = 1.0f + e2;
    const float p1  = 1.0f / den;
    const float p2  = e2 / den;

    const int tok = tile * 64 + lane;

    float4 wv;
    wv.x = (i1 == 0) ? p1 : ((i2 == 0) ? p2 : 0.0f);
    wv.y = (i1 == 1) ? p1 : ((i2 == 1) ? p2 : 0.0f);
    wv.z = (i1 == 2) ? p1 : ((i2 == 2) ? p2 : 0.0f);
    wv.w = (i1 == 3) ? p1 : ((i2 == 3) ? p2 : 0.0f);
    reinterpret_cast<float4*>(wout)[tok] = wv;

    float2 iv;
    iv.x = (float)i1;
    iv.y = (float)i2;
    reinterpret_cast<float2*>(iout)[tok] = iv;
}

extern "C" void kernel_launch(void* const* d_in, const int* in_sizes, int n_in,
                              void* d_out, int out_size, void* d_ws, size_t ws_size,
                              hipStream_t stream) {
    const float* x = (const float*)d_in[0];
    const float* W = (const float*)d_in[1];
    const int n = in_sizes[0] / EMBED_DIM;   // 2097152

    float* wout = (float*)d_out;                    // n*4 floats
    float* iout = wout + (size_t)n * NUM_EXPERTS;   // n*2 indices stored as float

    hipLaunchKernelGGL(gate_kernel, dim3(NBLOCKS), dim3(THREADS), 0, stream,
                       x, W, wout, iout, n);
}

// Round 11
// 115.020 us; speedup vs baseline: 1.3199x; 1.0027x over previous
//
#include <hip/hip_runtime.h>
#include <math.h>

#define EMBED_DIM 64
#define NUM_EXPERTS 4
#define THREADS 128                 // 2 INDEPENDENT waves per block
#define TOKS_PER_WAVE 32            // halved tile: 32 tokens = 8 KB per wave
#define TILE_CHUNKS 512             // 32 tokens * 16 float4
#define NBLOCKS 32768               // n / 64 tokens-per-block

// Occupancy probe: halve the per-wave tile (64 -> 32 tokens, 16 -> 8 KB)
// so LDS allows 10 blocks/CU = 20 waves/CU (was 10). Tests whether the
// ~5.1 TB/s plateau (identical across DMA/reg staging and all schedules)
// is demand-underlap (more waves -> smoother read demand -> faster) or a
// per-CU read-path in-flight cap (-> neutral -> roofline).
// Staging uses all 64 lanes (8 coalesced 1KB loads); compute uses lanes
// 0-31 only (one token per lane — the sequential chain can't be split).
// VALU was ~12% busy, so idling half the lanes there is free.
//
// Arithmetic is bit-identical to the passing kernels: strictly sequential
// f32 mul-then-add chain per logit (no FMA contraction; pragma disables
// -ffp-contract=fast), matching numpy einsum's sum-of-products order.
// XOR chunk swizzle applied at the LDS write and the same XOR at the read
// -> bank-conflict-free at both ends; global loads purely linear.
__global__ __launch_bounds__(THREADS) void gate_kernel(
    const float* __restrict__ x,
    const float* __restrict__ W,
    float* __restrict__ wout,     // [n,4] dense routing weights
    float* __restrict__ iout,     // [n,2] top-k indices, stored as float
    int n)
{
#pragma clang fp contract(off)
    __shared__ float4 lds[2 * TILE_CHUNKS];   // one 8KB tile per wave

    const int lane = threadIdx.x & 63;
    const int wid  = threadIdx.x >> 6;               // wave in block: 0/1
    const int tile = blockIdx.x * 2 + wid;           // this wave's tile
    float4* tilebuf = &lds[wid * TILE_CHUNKS];

    const float4* x4 = reinterpret_cast<const float4*>(x);
    const float4* W4 = reinterpret_cast<const float4*>(W);

    // 8 linear, fully-coalesced 1KB loads: global chunk G = i*64 + lane.
    const size_t tileChunk = (size_t)tile * TILE_CHUNKS;
    float4 r[8];
    #pragma unroll
    for (int i = 0; i < 8; ++i) {
        r[i] = x4[tileChunk + i * 64 + lane];
    }

    // Swizzled LDS writes: global chunk G=(tk<<4)|c -> (tk<<4)|(c^(tk&7)).
    // Each instruction still writes a contiguous 1KB span (XOR permutes
    // within 256B rows) -> conflict-free.
    #pragma unroll
    for (int i = 0; i < 8; ++i) {
        const int G  = i * 64 + lane;
        const int tk = G >> 4;
        const int c  = G & 15;
        tilebuf[(tk << 4) | (c ^ (tk & 7))] = r[i];
    }
    __builtin_amdgcn_sched_barrier(0);   // keep reads below the writes

    if (lane < TOKS_PER_WAVE) {
        float s0 = 0.0f, s1 = 0.0f, s2 = 0.0f, s3 = 0.0f;
        #pragma unroll
        for (int j = 0; j < 16; ++j) {
            const float4 xv = tilebuf[(lane << 4) | (j ^ (lane & 7))];
            const float4 a = W4[ 0 + j];
            const float4 b = W4[16 + j];
            const float4 c = W4[32 + j];
            const float4 d = W4[48 + j];
            // strict d-order, mul rounded then add rounded (no contraction):
            s0 = s0 + xv.x * a.x; s0 = s0 + xv.y * a.y;
            s0 = s0 + xv.z * a.z; s0 = s0 + xv.w * a.w;
            s1 = s1 + xv.x * b.x; s1 = s1 + xv.y * b.y;
            s1 = s1 + xv.z * b.z; s1 = s1 + xv.w * b.w;
            s2 = s2 + xv.x * c.x; s2 = s2 + xv.y * c.y;
            s2 = s2 + xv.z * c.z; s2 = s2 + xv.w * c.w;
            s3 = s3 + xv.x * d.x; s3 = s3 + xv.y * d.y;
            s3 = s3 + xv.z * d.z; s3 = s3 + xv.w * d.w;
        }

        // top-1: strict > -> ties to LOWER index (lax.top_k semantics).
        int   i1 = 0;  float v1 = s0;
        if (s1 > v1) { v1 = s1; i1 = 1; }
        if (s2 > v1) { v1 = s2; i1 = 2; }
        if (s3 > v1) { v1 = s3; i1 = 3; }
        int   i2 = -1; float v2 = -INFINITY;
        if (i1 != 0 && s0 > v2) { v2 = s0; i2 = 0; }
        if (i1 != 1 && s1 > v2) { v2 = s1; i2 = 1; }
        if (i1 != 2 && s2 > v2) { v2 = s2; i2 = 2; }
        if (i1 != 3 && s3 > v2) { v2 = s3; i2 = 3; }

        const float e2  = expf(v2 - v1);
        const float den = 1.0f + e2;
        const float p1  = 1.0f / den;
        const float p2  = e2 / den;

        const int tok = tile * TOKS_PER_WAVE + lane;

        float4 wv;
        wv.x = (i1 == 0) ? p1 : ((i2 == 0) ? p2 : 0.0f);
        wv.y = (i1 == 1) ? p1 : ((i2 == 1) ? p2 : 0.0f);
        wv.z = (i1 == 2) ? p1 : ((i2 == 2) ? p2 : 0.0f);
        wv.w = (i1 == 3) ? p1 : ((i2 == 3) ? p2 : 0.0f);
        reinterpret_cast<float4*>(wout)[tok] = wv;

        float2 iv;
        iv.x = (float)i1;
        iv.y = (float)i2;
        reinterpret_cast<float2*>(iout)[tok] = iv;
    }
}

extern "C" void kernel_launch(void* const* d_in, const int* in_sizes, int n_in,
                              void* d_out, int out_size, void* d_ws, size_t ws_size,
                              hipStream_t stream) {
    const float* x = (const float*)d_in[0];
    const float* W = (const float*)d_in[1];
    const int n = in_sizes[0] / EMBED_DIM;   // 2097152

    float* wout = (float*)d_out;                    // n*4 floats
    float* iout = wout + (size_t)n * NUM_EXPERTS;   // n*2 indices stored as float

    hipLaunchKernelGGL(gate_kernel, dim3(NBLOCKS), dim3(THREADS), 0, stream,
                       x, W, wout, iout, n);
}